// Round 6
// baseline (214.922 us; speedup 1.0000x reference)
//
#include <hip/hip_runtime.h>
#include <hip/hip_bf16.h>
#include <math.h>

#define NPTS 2048
#define BN   16384
#define KNN_K 32
typedef unsigned long long u64;
#define INF64 0xFFFFFFFFFFFFFFFFull

__device__ __forceinline__ u64 umin64(u64 a, u64 b) { return a < b ? a : b; }

// ---------------- Kernel A: exact kNN via prune + bitonic sort ----------------
__global__ __launch_bounds__(256) void knn_kernel(const float* __restrict__ pts,
                                                  int* __restrict__ knn) {
    __shared__ float px[NPTS], py[NPTS], pz[NPTS];
    __shared__ u64 surv[4][128];
    const int b = blockIdx.x >> 9;
    const int qbase = (blockIdx.x & 511) << 2;
    const float* pb = pts + (size_t)b * NPTS * 3;
    for (int i = threadIdx.x; i < NPTS; i += 256) {
        px[i] = pb[i * 3 + 0];
        py[i] = pb[i * 3 + 1];
        pz[i] = pb[i * 3 + 2];
    }
    __syncthreads();
    const int wave = threadIdx.x >> 6, lane = threadIdx.x & 63;
    const int q = qbase + wave;
    const float qx = px[q], qy = py[q], qz = pz[q];

    // exact reference-order distances (no FMA contraction, correctly-rounded sqrt)
    float d[32];
#pragma unroll
    for (int t = 0; t < 32; ++t) {
        int j = t * 64 + lane;
        float dx = __fsub_rn(qx, px[j]);
        float dy = __fsub_rn(qy, py[j]);
        float dz = __fsub_rn(qz, pz[j]);
        float d2 = __fadd_rn(__fadd_rn(__fmul_rn(dx, dx), __fmul_rn(dy, dy)),
                             __fmul_rn(dz, dz));
        d[t] = __fsqrt_rn(d2);
    }

    float lmin = d[0];
#pragma unroll
    for (int t = 1; t < 32; ++t) lmin = fminf(lmin, d[t]);

    // bitonic sort of 64 lane-minima
    float v = lmin;
#pragma unroll
    for (int k = 2; k <= 64; k <<= 1) {
#pragma unroll
        for (int j = k >> 1; j > 0; j >>= 1) {
            float o = __shfl_xor(v, j, 64);
            bool up = ((lane & k) == 0);
            bool low = ((lane & j) == 0);
            float mn = fminf(v, o), mx = fmaxf(v, o);
            v = (low == up) ? mn : mx;
        }
    }
    float Tpre = __shfl(v, 31, 64);   // >= 32nd-smallest global distance

    u64* sw = surv[wave];
    unsigned cnt = 0;
#pragma unroll
    for (int t = 0; t < 32; ++t) {
        bool sel = (d[t] <= Tpre);
        u64 m = __ballot(sel);
        if (sel) {
            u64 key = ((u64)__float_as_uint(d[t]) << 32) | (unsigned)(t * 64 + lane);
            unsigned pos = cnt + (unsigned)__popcll(m & ((1ull << lane) - 1ull));
            if (pos < 128) sw[pos] = key;
        }
        cnt += (unsigned)__popcll(m);
    }

    int* kout = knn + ((size_t)b * NPTS + q) * KNN_K;
    __asm__ volatile("s_waitcnt lgkmcnt(0)" ::: "memory");  // own-wave LDS W->R fence

    if (cnt <= 64) {
        u64 key = (lane < (int)cnt) ? sw[lane] : INF64;
#pragma unroll
        for (int k = 2; k <= 64; k <<= 1) {
#pragma unroll
            for (int j = k >> 1; j > 0; j >>= 1) {
                u64 o = __shfl_xor(key, j, 64);
                bool up = ((lane & k) == 0);
                bool low = ((lane & j) == 0);
                bool lt = key < o;
                u64 mn = lt ? key : o, mx = lt ? o : key;
                key = (low == up) ? mn : mx;
            }
        }
        if (lane < KNN_K) kout[lane] = (int)(unsigned)(key & 0xFFFFFFFFull);
    } else {
        // rare exact fallback (survivors > 64)
        unsigned fmask = 0xFFFFFFFFu;
        for (int r = 0; r < KNN_K; ++r) {
            u64 mm = INF64;
#pragma unroll
            for (int t = 0; t < 32; ++t) {
                u64 kk = ((u64)__float_as_uint(d[t]) << 32) | (unsigned)(t * 64 + lane);
                mm = umin64(mm, ((fmask >> t) & 1u) ? kk : INF64);
            }
#pragma unroll
            for (int s = 1; s < 64; s <<= 1) mm = umin64(mm, __shfl_xor(mm, s, 64));
            unsigned j = (unsigned)(mm & 0xFFFFFFFFull);
            if (lane == (int)(j & 63)) fmask &= ~(1u << (j >> 6));
            if (lane == 0) kout[r] = (int)j;
        }
    }
}

// ---------------- Kernel B: fused MLP (layers 1..3) -> f3 [BN][256] ----------------
// 1024 blocks x 256 threads; 16 points per block.
// Phase 0: layers 1+2 -> h2 tile in LDS (thread = point x 8-ch chunk).
// Phase 1: layer 3 GEMM (thread = 2 points x 8 channels, h2 from LDS broadcast,
//          W3 streamed coalesced from L2).
__global__ __launch_bounds__(256, 4) void mlp123_kernel(const float* __restrict__ pts,
        const float* __restrict__ W1, const float* __restrict__ b1,
        const float* __restrict__ W2, const float* __restrict__ b2,
        const float* __restrict__ W3, const float* __restrict__ b3,
        float* __restrict__ f3) {
    __shared__ float h2s[16][128];   // 8 KB
    const int tid = threadIdx.x;
    const int p0 = blockIdx.x << 4;

    // ---- phase 0: layers 1+2 for this block's 16 points ----
    {
        const int pl = tid >> 4;      // local point 0..15
        const int ch = tid & 15;      // 8-channel chunk of h2
        const float* pp = pts + (size_t)(p0 + pl) * 3;
        float x = pp[0], y = pp[1], z = pp[2];
        float h1[64];
#pragma unroll
        for (int i = 0; i < 64; ++i) {
            float a = fmaf(x, W1[i], fmaf(y, W1[64 + i], fmaf(z, W1[128 + i], b1[i])));
            h1[i] = fmaxf(a, 0.f);
        }
        float4 a0 = make_float4(0.f, 0.f, 0.f, 0.f);
        float4 a1 = make_float4(0.f, 0.f, 0.f, 0.f);
        const float* w2 = W2 + ch * 8;
#pragma unroll 4
        for (int i = 0; i < 64; ++i) {
            float h = h1[i];
            float4 w0 = *(const float4*)(w2 + i * 128);
            float4 w1 = *(const float4*)(w2 + i * 128 + 4);
            a0.x = fmaf(h, w0.x, a0.x); a0.y = fmaf(h, w0.y, a0.y);
            a0.z = fmaf(h, w0.z, a0.z); a0.w = fmaf(h, w0.w, a0.w);
            a1.x = fmaf(h, w1.x, a1.x); a1.y = fmaf(h, w1.y, a1.y);
            a1.z = fmaf(h, w1.z, a1.z); a1.w = fmaf(h, w1.w, a1.w);
        }
        float4 bb0 = *(const float4*)(b2 + ch * 8);
        float4 bb1 = *(const float4*)(b2 + ch * 8 + 4);
        float4 r0 = make_float4(fmaxf(a0.x + bb0.x, 0.f), fmaxf(a0.y + bb0.y, 0.f),
                                fmaxf(a0.z + bb0.z, 0.f), fmaxf(a0.w + bb0.w, 0.f));
        float4 r1 = make_float4(fmaxf(a1.x + bb1.x, 0.f), fmaxf(a1.y + bb1.y, 0.f),
                                fmaxf(a1.z + bb1.z, 0.f), fmaxf(a1.w + bb1.w, 0.f));
        *(float4*)&h2s[pl][ch * 8]     = r0;
        *(float4*)&h2s[pl][ch * 8 + 4] = r1;
    }
    __syncthreads();

    // ---- phase 1: layer 3, register-blocked 2 points x 8 channels ----
    const int pg = tid >> 5;          // 0..7 -> points pg*2, pg*2+1
    const int c0 = (tid & 31) * 8;
    float4 acc00 = make_float4(0.f, 0.f, 0.f, 0.f);
    float4 acc01 = make_float4(0.f, 0.f, 0.f, 0.f);
    float4 acc10 = make_float4(0.f, 0.f, 0.f, 0.f);
    float4 acc11 = make_float4(0.f, 0.f, 0.f, 0.f);
#pragma unroll 2
    for (int k4 = 0; k4 < 32; ++k4) {
        float4 ha = *(const float4*)&h2s[pg * 2 + 0][k4 * 4];
        float4 hb = *(const float4*)&h2s[pg * 2 + 1][k4 * 4];
#pragma unroll
        for (int u = 0; u < 4; ++u) {
            const float* wr = W3 + (size_t)(k4 * 4 + u) * 256 + c0;
            float4 w0 = *(const float4*)wr;
            float4 w1 = *(const float4*)(wr + 4);
            float hau = (u == 0) ? ha.x : (u == 1) ? ha.y : (u == 2) ? ha.z : ha.w;
            float hbu = (u == 0) ? hb.x : (u == 1) ? hb.y : (u == 2) ? hb.z : hb.w;
            acc00.x = fmaf(hau, w0.x, acc00.x); acc00.y = fmaf(hau, w0.y, acc00.y);
            acc00.z = fmaf(hau, w0.z, acc00.z); acc00.w = fmaf(hau, w0.w, acc00.w);
            acc01.x = fmaf(hau, w1.x, acc01.x); acc01.y = fmaf(hau, w1.y, acc01.y);
            acc01.z = fmaf(hau, w1.z, acc01.z); acc01.w = fmaf(hau, w1.w, acc01.w);
            acc10.x = fmaf(hbu, w0.x, acc10.x); acc10.y = fmaf(hbu, w0.y, acc10.y);
            acc10.z = fmaf(hbu, w0.z, acc10.z); acc10.w = fmaf(hbu, w0.w, acc10.w);
            acc11.x = fmaf(hbu, w1.x, acc11.x); acc11.y = fmaf(hbu, w1.y, acc11.y);
            acc11.z = fmaf(hbu, w1.z, acc11.z); acc11.w = fmaf(hbu, w1.w, acc11.w);
        }
    }
    float4 b3l = *(const float4*)(b3 + c0);
    float4 b3h = *(const float4*)(b3 + c0 + 4);
    {
        float* o = f3 + ((size_t)(p0 + pg * 2 + 0)) * 256 + c0;
        float4 r0 = make_float4(fmaxf(acc00.x + b3l.x, 0.f), fmaxf(acc00.y + b3l.y, 0.f),
                                fmaxf(acc00.z + b3l.z, 0.f), fmaxf(acc00.w + b3l.w, 0.f));
        float4 r1 = make_float4(fmaxf(acc01.x + b3h.x, 0.f), fmaxf(acc01.y + b3h.y, 0.f),
                                fmaxf(acc01.z + b3h.z, 0.f), fmaxf(acc01.w + b3h.w, 0.f));
        *(float4*)o = r0;
        *(float4*)(o + 4) = r1;
    }
    {
        float* o = f3 + ((size_t)(p0 + pg * 2 + 1)) * 256 + c0;
        float4 r0 = make_float4(fmaxf(acc10.x + b3l.x, 0.f), fmaxf(acc10.y + b3l.y, 0.f),
                                fmaxf(acc10.z + b3l.z, 0.f), fmaxf(acc10.w + b3l.w, 0.f));
        float4 r1 = make_float4(fmaxf(acc11.x + b3h.x, 0.f), fmaxf(acc11.y + b3h.y, 0.f),
                                fmaxf(acc11.z + b3h.z, 0.f), fmaxf(acc11.w + b3h.w, 0.f));
        *(float4*)o = r0;
        *(float4*)(o + 4) = r1;
    }
}

// ---------------- Kernel C: gather + mean, float4 (wave reads full row) ----------------
__global__ __launch_bounds__(256) void gather_mean_kernel(const float* __restrict__ f3,
        const int* __restrict__ knn, float* __restrict__ out) {
    int wave = threadIdx.x >> 6, lane = threadIdx.x & 63;
    int q = blockIdx.x * 4 + wave;     // 4096 blocks
    int b = q >> 11;
    const int* kq = knn + (size_t)q * KNN_K;
    const float4* fb = (const float4*)(f3 + (size_t)b * NPTS * 256);
    float4 acc = make_float4(0.f, 0.f, 0.f, 0.f);
#pragma unroll
    for (int k = 0; k < KNN_K; ++k) {
        int j = kq[k];
        float4 v2 = fb[(size_t)j * 64 + lane];
        acc.x += v2.x; acc.y += v2.y; acc.z += v2.z; acc.w += v2.w;
    }
    float4 r = make_float4(acc.x * 0.03125f, acc.y * 0.03125f,
                           acc.z * 0.03125f, acc.w * 0.03125f);
    *(float4*)(out + (size_t)q * 256 + lane * 4) = r;
}

extern "C" void kernel_launch(void* const* d_in, const int* in_sizes, int n_in,
                              void* d_out, int out_size, void* d_ws, size_t ws_size,
                              hipStream_t stream) {
    const float* pts = (const float*)d_in[0];
    const float* W1  = (const float*)d_in[1];
    const float* b1  = (const float*)d_in[2];
    const float* W2  = (const float*)d_in[3];
    const float* b2  = (const float*)d_in[4];
    const float* W3  = (const float*)d_in[5];
    const float* b3  = (const float*)d_in[6];
    float* out = (float*)d_out;
    char* ws = (char*)d_ws;
    int*   knn = (int*)ws;                               // 2 MB
    float* f3  = (float*)(ws + ((size_t)2 << 20));       // 16.8 MB

    hipLaunchKernelGGL(knn_kernel,         dim3(4096), dim3(256), 0, stream, pts, knn);
    hipLaunchKernelGGL(mlp123_kernel,      dim3(1024), dim3(256), 0, stream,
                       pts, W1, b1, W2, b2, W3, b3, f3);
    hipLaunchKernelGGL(gather_mean_kernel, dim3(4096), dim3(256), 0, stream, f3, knn, out);
}

// Round 12
// 190.897 us; speedup vs baseline: 1.1259x; 1.1259x over previous
//
#include <hip/hip_runtime.h>
#include <hip/hip_bf16.h>
#include <math.h>

#define NPTS 2048
#define BN   16384
#define KNN_K 32
typedef unsigned long long u64;
typedef float f32x4 __attribute__((ext_vector_type(4)));   // native vector for nontemporal store
#define INF64 0xFFFFFFFFFFFFFFFFull

__device__ __forceinline__ u64 umin64(u64 a, u64 b) { return a < b ? a : b; }

// ---------------- Kernel A: exact kNN via prune + bitonic sort ----------------
__global__ __launch_bounds__(256) void knn_kernel(const float* __restrict__ pts,
                                                  int* __restrict__ knn) {
    __shared__ float px[NPTS], py[NPTS], pz[NPTS];
    __shared__ u64 surv[4][128];
    const int b = blockIdx.x >> 9;
    const int qbase = (blockIdx.x & 511) << 2;
    const float* pb = pts + (size_t)b * NPTS * 3;
    for (int i = threadIdx.x; i < NPTS; i += 256) {
        px[i] = pb[i * 3 + 0];
        py[i] = pb[i * 3 + 1];
        pz[i] = pb[i * 3 + 2];
    }
    __syncthreads();
    const int wave = threadIdx.x >> 6, lane = threadIdx.x & 63;
    const int q = qbase + wave;
    const float qx = px[q], qy = py[q], qz = pz[q];

    // exact reference-order distances (no FMA contraction, correctly-rounded sqrt)
    float d[32];
#pragma unroll
    for (int t = 0; t < 32; ++t) {
        int j = t * 64 + lane;
        float dx = __fsub_rn(qx, px[j]);
        float dy = __fsub_rn(qy, py[j]);
        float dz = __fsub_rn(qz, pz[j]);
        float d2 = __fadd_rn(__fadd_rn(__fmul_rn(dx, dx), __fmul_rn(dy, dy)),
                             __fmul_rn(dz, dz));
        d[t] = __fsqrt_rn(d2);
    }

    float lmin = d[0];
#pragma unroll
    for (int t = 1; t < 32; ++t) lmin = fminf(lmin, d[t]);

    // bitonic sort of 64 lane-minima
    float v = lmin;
#pragma unroll
    for (int k = 2; k <= 64; k <<= 1) {
#pragma unroll
        for (int j = k >> 1; j > 0; j >>= 1) {
            float o = __shfl_xor(v, j, 64);
            bool up = ((lane & k) == 0);
            bool low = ((lane & j) == 0);
            float mn = fminf(v, o), mx = fmaxf(v, o);
            v = (low == up) ? mn : mx;
        }
    }
    float Tpre = __shfl(v, 31, 64);   // >= 32nd-smallest global distance

    u64* sw = surv[wave];
    unsigned cnt = 0;
#pragma unroll
    for (int t = 0; t < 32; ++t) {
        bool sel = (d[t] <= Tpre);
        u64 m = __ballot(sel);
        if (sel) {
            u64 key = ((u64)__float_as_uint(d[t]) << 32) | (unsigned)(t * 64 + lane);
            unsigned pos = cnt + (unsigned)__popcll(m & ((1ull << lane) - 1ull));
            if (pos < 128) sw[pos] = key;
        }
        cnt += (unsigned)__popcll(m);
    }

    int* kout = knn + ((size_t)b * NPTS + q) * KNN_K;
    __asm__ volatile("s_waitcnt lgkmcnt(0)" ::: "memory");  // own-wave LDS W->R fence

    if (cnt <= 64) {
        u64 key = (lane < (int)cnt) ? sw[lane] : INF64;
#pragma unroll
        for (int k = 2; k <= 64; k <<= 1) {
#pragma unroll
            for (int j = k >> 1; j > 0; j >>= 1) {
                u64 o = __shfl_xor(key, j, 64);
                bool up = ((lane & k) == 0);
                bool low = ((lane & j) == 0);
                bool lt = key < o;
                u64 mn = lt ? key : o, mx = lt ? o : key;
                key = (low == up) ? mn : mx;
            }
        }
        if (lane < KNN_K) kout[lane] = (int)(unsigned)(key & 0xFFFFFFFFull);
    } else {
        // rare exact fallback (survivors > 64)
        unsigned fmask = 0xFFFFFFFFu;
        for (int r = 0; r < KNN_K; ++r) {
            u64 mm = INF64;
#pragma unroll
            for (int t = 0; t < 32; ++t) {
                u64 kk = ((u64)__float_as_uint(d[t]) << 32) | (unsigned)(t * 64 + lane);
                mm = umin64(mm, ((fmask >> t) & 1u) ? kk : INF64);
            }
#pragma unroll
            for (int s = 1; s < 64; s <<= 1) mm = umin64(mm, __shfl_xor(mm, s, 64));
            unsigned j = (unsigned)(mm & 0xFFFFFFFFull);
            if (lane == (int)(j & 63)) fmask &= ~(1u << (j >> 6));
            if (lane == 0) kout[r] = (int)j;
        }
    }
}

// ---------------- Kernel B: fused MLP (layers 1..3) -> f3 [BN][256] ----------------
// 2048 blocks x 256 threads; 8 points per block (8 blocks/CU for occupancy).
// Phase 0: wave-per-point; h1 one-channel-per-lane shared via shfl; each lane
//          computes 2 h2 channels for 2 points per float2 W2 load.
// Phase 1: wave per 2 points; lane per 4 channels; one W3 float4 row-slice
//          feeds 8 FMA (2 points).
__global__ __launch_bounds__(256, 8) void mlp123_kernel(const float* __restrict__ pts,
        const float* __restrict__ W1, const float* __restrict__ b1,
        const float* __restrict__ W2, const float* __restrict__ b2,
        const float* __restrict__ W3, const float* __restrict__ b3,
        float* __restrict__ f3) {
    __shared__ float h2s[8][128];   // 4 KB
    const int tid = threadIdx.x;
    const int wv = tid >> 6, lane = tid & 63;
    const int p0 = blockIdx.x << 3;

    // ---- phase 0: layers 1+2, wave wv handles points wv and wv+4 ----
    {
        const float w1a = W1[lane], w1b = W1[64 + lane], w1c = W1[128 + lane];
        const float b1v = b1[lane];
        const int pA = __builtin_amdgcn_readfirstlane(p0 + wv);
        const int pB = __builtin_amdgcn_readfirstlane(p0 + wv + 4);
        const float* ppA = pts + (size_t)pA * 3;
        const float* ppB = pts + (size_t)pB * 3;
        float xA = ppA[0], yA = ppA[1], zA = ppA[2];
        float xB = ppB[0], yB = ppB[1], zB = ppB[2];
        float h1A = fmaxf(fmaf(xA, w1a, fmaf(yA, w1b, fmaf(zA, w1c, b1v))), 0.f);
        float h1B = fmaxf(fmaf(xB, w1a, fmaf(yB, w1b, fmaf(zB, w1c, b1v))), 0.f);
        float2 b2v = *(const float2*)(b2 + 2 * lane);
        float a0A = b2v.x, a1A = b2v.y, a0B = b2v.x, a1B = b2v.y;
#pragma unroll
        for (int i = 0; i < 64; ++i) {
            float2 w = *(const float2*)(W2 + i * 128 + 2 * lane);
            float hA = __shfl(h1A, i, 64);
            float hB = __shfl(h1B, i, 64);
            a0A = fmaf(hA, w.x, a0A); a1A = fmaf(hA, w.y, a1A);
            a0B = fmaf(hB, w.x, a0B); a1B = fmaf(hB, w.y, a1B);
        }
        *(float2*)&h2s[wv][2 * lane]     = make_float2(fmaxf(a0A, 0.f), fmaxf(a1A, 0.f));
        *(float2*)&h2s[wv + 4][2 * lane] = make_float2(fmaxf(a0B, 0.f), fmaxf(a1B, 0.f));
    }
    __syncthreads();

    // ---- phase 1: layer 3; wave wv -> points 2wv, 2wv+1; lane -> 4 channels ----
    const int c = lane * 4;
    const int pa = 2 * wv, pb = 2 * wv + 1;
    float4 accA = make_float4(0.f, 0.f, 0.f, 0.f);
    float4 accB = make_float4(0.f, 0.f, 0.f, 0.f);
#pragma unroll 4
    for (int k = 0; k < 128; ++k) {
        float4 w = *(const float4*)(W3 + (size_t)k * 256 + c);
        float ha = h2s[pa][k];
        float hb = h2s[pb][k];
        accA.x = fmaf(ha, w.x, accA.x); accA.y = fmaf(ha, w.y, accA.y);
        accA.z = fmaf(ha, w.z, accA.z); accA.w = fmaf(ha, w.w, accA.w);
        accB.x = fmaf(hb, w.x, accB.x); accB.y = fmaf(hb, w.y, accB.y);
        accB.z = fmaf(hb, w.z, accB.z); accB.w = fmaf(hb, w.w, accB.w);
    }
    float4 bb = *(const float4*)(b3 + c);
    float4 rA = make_float4(fmaxf(accA.x + bb.x, 0.f), fmaxf(accA.y + bb.y, 0.f),
                            fmaxf(accA.z + bb.z, 0.f), fmaxf(accA.w + bb.w, 0.f));
    float4 rB = make_float4(fmaxf(accB.x + bb.x, 0.f), fmaxf(accB.y + bb.y, 0.f),
                            fmaxf(accB.z + bb.z, 0.f), fmaxf(accB.w + bb.w, 0.f));
    *(float4*)(f3 + ((size_t)(p0 + pa)) * 256 + c) = rA;
    *(float4*)(f3 + ((size_t)(p0 + pb)) * 256 + c) = rB;
}

// ---------------- Kernel C: gather + mean; batch pinned to XCD via blockIdx&7 ----------------
__global__ __launch_bounds__(256) void gather_mean_kernel(const float* __restrict__ f3,
        const int* __restrict__ knn, float* __restrict__ out) {
    int wave = threadIdx.x >> 6, lane = threadIdx.x & 63;
    // Batch = blockIdx&7: round-robin dispatch keeps each batch's 2.1 MB f3
    // slab resident in a single XCD's L2.
    int b  = blockIdx.x & 7;
    int qg = blockIdx.x >> 3;          // 0..511
    int q  = b * NPTS + qg * 4 + wave;
    const int* kq = knn + (size_t)q * KNN_K;
    const float4* fb = (const float4*)(f3 + (size_t)b * NPTS * 256);
    float4 acc = make_float4(0.f, 0.f, 0.f, 0.f);
#pragma unroll
    for (int k = 0; k < KNN_K; ++k) {
        int j = kq[k];
        float4 v2 = fb[(size_t)j * 64 + lane];
        acc.x += v2.x; acc.y += v2.y; acc.z += v2.z; acc.w += v2.w;
    }
    f32x4 r;
    r.x = acc.x * 0.03125f; r.y = acc.y * 0.03125f;
    r.z = acc.z * 0.03125f; r.w = acc.w * 0.03125f;
    // out is never re-read: nontemporal store keeps f3 resident in L2
    // (native ext_vector type: __builtin_nontemporal_store rejects HIP_vector_type)
    __builtin_nontemporal_store(r, (f32x4*)(out + (size_t)q * 256 + lane * 4));
}

extern "C" void kernel_launch(void* const* d_in, const int* in_sizes, int n_in,
                              void* d_out, int out_size, void* d_ws, size_t ws_size,
                              hipStream_t stream) {
    const float* pts = (const float*)d_in[0];
    const float* W1  = (const float*)d_in[1];
    const float* b1  = (const float*)d_in[2];
    const float* W2  = (const float*)d_in[3];
    const float* b2  = (const float*)d_in[4];
    const float* W3  = (const float*)d_in[5];
    const float* b3  = (const float*)d_in[6];
    float* out = (float*)d_out;
    char* ws = (char*)d_ws;
    int*   knn = (int*)ws;                               // 2 MB
    float* f3  = (float*)(ws + ((size_t)2 << 20));       // 16.8 MB

    hipLaunchKernelGGL(knn_kernel,         dim3(4096), dim3(256), 0, stream, pts, knn);
    hipLaunchKernelGGL(mlp123_kernel,      dim3(2048), dim3(256), 0, stream,
                       pts, W1, b1, W2, b2, W3, b3, f3);
    hipLaunchKernelGGL(gather_mean_kernel, dim3(4096), dim3(256), 0, stream, f3, knn, out);
}

// Round 13
// 171.188 us; speedup vs baseline: 1.2555x; 1.1151x over previous
//
#include <hip/hip_runtime.h>
#include <hip/hip_bf16.h>
#include <math.h>

#define NPTS 2048
#define BN   16384
#define KNN_K 32
typedef unsigned long long u64;
typedef float f32x4 __attribute__((ext_vector_type(4)));
#define INF64 0xFFFFFFFFFFFFFFFFull

__device__ __forceinline__ u64 umin64(u64 a, u64 b) { return a < b ? a : b; }

// ---------------- Kernel A: exact kNN via prune + bitonic sort ----------------
__global__ __launch_bounds__(256) void knn_kernel(const float* __restrict__ pts,
                                                  int* __restrict__ knn) {
    __shared__ float px[NPTS], py[NPTS], pz[NPTS];
    __shared__ u64 surv[4][128];
    const int b = blockIdx.x >> 9;
    const int qbase = (blockIdx.x & 511) << 2;
    const float* pb = pts + (size_t)b * NPTS * 3;
    for (int i = threadIdx.x; i < NPTS; i += 256) {
        px[i] = pb[i * 3 + 0];
        py[i] = pb[i * 3 + 1];
        pz[i] = pb[i * 3 + 2];
    }
    __syncthreads();
    const int wave = threadIdx.x >> 6, lane = threadIdx.x & 63;
    const int q = qbase + wave;
    const float qx = px[q], qy = py[q], qz = pz[q];

    // exact reference-order distances (no FMA contraction, correctly-rounded sqrt)
    float d[32];
#pragma unroll
    for (int t = 0; t < 32; ++t) {
        int j = t * 64 + lane;
        float dx = __fsub_rn(qx, px[j]);
        float dy = __fsub_rn(qy, py[j]);
        float dz = __fsub_rn(qz, pz[j]);
        float d2 = __fadd_rn(__fadd_rn(__fmul_rn(dx, dx), __fmul_rn(dy, dy)),
                             __fmul_rn(dz, dz));
        d[t] = __fsqrt_rn(d2);
    }

    float lmin = d[0];
#pragma unroll
    for (int t = 1; t < 32; ++t) lmin = fminf(lmin, d[t]);

    // bitonic sort of 64 lane-minima
    float v = lmin;
#pragma unroll
    for (int k = 2; k <= 64; k <<= 1) {
#pragma unroll
        for (int j = k >> 1; j > 0; j >>= 1) {
            float o = __shfl_xor(v, j, 64);
            bool up = ((lane & k) == 0);
            bool low = ((lane & j) == 0);
            float mn = fminf(v, o), mx = fmaxf(v, o);
            v = (low == up) ? mn : mx;
        }
    }
    float Tpre = __shfl(v, 31, 64);   // >= 32nd-smallest global distance

    u64* sw = surv[wave];
    unsigned cnt = 0;
#pragma unroll
    for (int t = 0; t < 32; ++t) {
        bool sel = (d[t] <= Tpre);
        u64 m = __ballot(sel);
        if (sel) {
            u64 key = ((u64)__float_as_uint(d[t]) << 32) | (unsigned)(t * 64 + lane);
            unsigned pos = cnt + (unsigned)__popcll(m & ((1ull << lane) - 1ull));
            if (pos < 128) sw[pos] = key;
        }
        cnt += (unsigned)__popcll(m);
    }

    int* kout = knn + ((size_t)b * NPTS + q) * KNN_K;
    __asm__ volatile("s_waitcnt lgkmcnt(0)" ::: "memory");  // own-wave LDS W->R fence

    if (cnt <= 64) {
        u64 key = (lane < (int)cnt) ? sw[lane] : INF64;
#pragma unroll
        for (int k = 2; k <= 64; k <<= 1) {
#pragma unroll
            for (int j = k >> 1; j > 0; j >>= 1) {
                u64 o = __shfl_xor(key, j, 64);
                bool up = ((lane & k) == 0);
                bool low = ((lane & j) == 0);
                bool lt = key < o;
                u64 mn = lt ? key : o, mx = lt ? o : key;
                key = (low == up) ? mn : mx;
            }
        }
        if (lane < KNN_K) kout[lane] = (int)(unsigned)(key & 0xFFFFFFFFull);
    } else {
        // rare exact fallback (survivors > 64)
        unsigned fmask = 0xFFFFFFFFu;
        for (int r = 0; r < KNN_K; ++r) {
            u64 mm = INF64;
#pragma unroll
            for (int t = 0; t < 32; ++t) {
                u64 kk = ((u64)__float_as_uint(d[t]) << 32) | (unsigned)(t * 64 + lane);
                mm = umin64(mm, ((fmask >> t) & 1u) ? kk : INF64);
            }
#pragma unroll
            for (int s = 1; s < 64; s <<= 1) mm = umin64(mm, __shfl_xor(mm, s, 64));
            unsigned j = (unsigned)(mm & 0xFFFFFFFFull);
            if (lane == (int)(j & 63)) fmask &= ~(1u << (j >> 6));
            if (lane == 0) kout[r] = (int)j;
        }
    }
}

// ---------------- Kernel B: fused MLP (layers 1..3) -> f3 [BN][256] ----------------
// 1024 blocks x 256 threads; 16 points per block; 4 blocks/CU (16 waves/CU).
// Wave wv owns points 4wv..4wv+3 through BOTH phases -> no __syncthreads, just
// an own-wave lgkmcnt fence (same idiom as knn's surv buffer).
// Phase 0: lane = h1 channel; h1 shared via shfl; lane computes 2 h2 channels
//          for its 4 points per float2 W2 load.
// Phase 1: lane = 4 channels x 4 points: one W3 float4 feeds 16 FMA
//          (halves issued W3 L2 traffic vs Pp=2: 2.15 GB/Pp).
__global__ __launch_bounds__(256, 8) void mlp123_kernel(const float* __restrict__ pts,
        const float* __restrict__ W1, const float* __restrict__ b1,
        const float* __restrict__ W2, const float* __restrict__ b2,
        const float* __restrict__ W3, const float* __restrict__ b3,
        float* __restrict__ f3) {
    __shared__ float h2s[16][128];   // 8 KB
    const int tid = threadIdx.x;
    const int wv = tid >> 6, lane = tid & 63;
    const int p0 = blockIdx.x << 4;
    const int pbase = wv * 4;        // this wave's local points

    // ---- phase 0: layers 1+2 for this wave's 4 points ----
    {
        const float w1a = W1[lane], w1b = W1[64 + lane], w1c = W1[128 + lane];
        const float b1v = b1[lane];
        float h1v[4];
#pragma unroll
        for (int p = 0; p < 4; ++p) {
            const int pp = __builtin_amdgcn_readfirstlane(p0 + pbase + p);
            const float* ptp = pts + (size_t)pp * 3;
            h1v[p] = fmaxf(fmaf(ptp[0], w1a, fmaf(ptp[1], w1b, fmaf(ptp[2], w1c, b1v))), 0.f);
        }
        float2 b2v = *(const float2*)(b2 + 2 * lane);
        float a0[4], a1[4];
#pragma unroll
        for (int p = 0; p < 4; ++p) { a0[p] = b2v.x; a1[p] = b2v.y; }
#pragma unroll
        for (int i = 0; i < 64; ++i) {
            float2 w = *(const float2*)(W2 + i * 128 + 2 * lane);
#pragma unroll
            for (int p = 0; p < 4; ++p) {
                float h = __shfl(h1v[p], i, 64);
                a0[p] = fmaf(h, w.x, a0[p]);
                a1[p] = fmaf(h, w.y, a1[p]);
            }
        }
#pragma unroll
        for (int p = 0; p < 4; ++p)
            *(float2*)&h2s[pbase + p][2 * lane] =
                make_float2(fmaxf(a0[p], 0.f), fmaxf(a1[p], 0.f));
    }
    // own-wave LDS write->read fence (phase 1 reads only this wave's rows)
    __asm__ volatile("s_waitcnt lgkmcnt(0)" ::: "memory");

    // ---- phase 1: layer 3; lane -> channels c0..c0+3, points pbase..pbase+3 ----
    const int c0 = lane * 4;
    float4 acc0 = make_float4(0.f, 0.f, 0.f, 0.f);
    float4 acc1 = make_float4(0.f, 0.f, 0.f, 0.f);
    float4 acc2 = make_float4(0.f, 0.f, 0.f, 0.f);
    float4 acc3 = make_float4(0.f, 0.f, 0.f, 0.f);
    for (int k4 = 0; k4 < 32; ++k4) {
        // uniform-broadcast b128 reads of this wave's h2 rows
        float4 h0 = *(const float4*)&h2s[pbase + 0][k4 * 4];
        float4 h1 = *(const float4*)&h2s[pbase + 1][k4 * 4];
        float4 h2 = *(const float4*)&h2s[pbase + 2][k4 * 4];
        float4 h3 = *(const float4*)&h2s[pbase + 3][k4 * 4];
#pragma unroll
        for (int u = 0; u < 4; ++u) {
            float4 w = *(const float4*)(W3 + (size_t)(k4 * 4 + u) * 256 + c0);
            float e0 = (u == 0) ? h0.x : (u == 1) ? h0.y : (u == 2) ? h0.z : h0.w;
            float e1 = (u == 0) ? h1.x : (u == 1) ? h1.y : (u == 2) ? h1.z : h1.w;
            float e2 = (u == 0) ? h2.x : (u == 1) ? h2.y : (u == 2) ? h2.z : h2.w;
            float e3 = (u == 0) ? h3.x : (u == 1) ? h3.y : (u == 2) ? h3.z : h3.w;
            acc0.x = fmaf(e0, w.x, acc0.x); acc0.y = fmaf(e0, w.y, acc0.y);
            acc0.z = fmaf(e0, w.z, acc0.z); acc0.w = fmaf(e0, w.w, acc0.w);
            acc1.x = fmaf(e1, w.x, acc1.x); acc1.y = fmaf(e1, w.y, acc1.y);
            acc1.z = fmaf(e1, w.z, acc1.z); acc1.w = fmaf(e1, w.w, acc1.w);
            acc2.x = fmaf(e2, w.x, acc2.x); acc2.y = fmaf(e2, w.y, acc2.y);
            acc2.z = fmaf(e2, w.z, acc2.z); acc2.w = fmaf(e2, w.w, acc2.w);
            acc3.x = fmaf(e3, w.x, acc3.x); acc3.y = fmaf(e3, w.y, acc3.y);
            acc3.z = fmaf(e3, w.z, acc3.z); acc3.w = fmaf(e3, w.w, acc3.w);
        }
    }
    float4 bb = *(const float4*)(b3 + c0);
    float4 r0 = make_float4(fmaxf(acc0.x + bb.x, 0.f), fmaxf(acc0.y + bb.y, 0.f),
                            fmaxf(acc0.z + bb.z, 0.f), fmaxf(acc0.w + bb.w, 0.f));
    float4 r1 = make_float4(fmaxf(acc1.x + bb.x, 0.f), fmaxf(acc1.y + bb.y, 0.f),
                            fmaxf(acc1.z + bb.z, 0.f), fmaxf(acc1.w + bb.w, 0.f));
    float4 r2 = make_float4(fmaxf(acc2.x + bb.x, 0.f), fmaxf(acc2.y + bb.y, 0.f),
                            fmaxf(acc2.z + bb.z, 0.f), fmaxf(acc2.w + bb.w, 0.f));
    float4 r3 = make_float4(fmaxf(acc3.x + bb.x, 0.f), fmaxf(acc3.y + bb.y, 0.f),
                            fmaxf(acc3.z + bb.z, 0.f), fmaxf(acc3.w + bb.w, 0.f));
    float* ob = f3 + ((size_t)(p0 + pbase)) * 256 + c0;
    *(float4*)(ob)           = r0;
    *(float4*)(ob + 256)     = r1;
    *(float4*)(ob + 512)     = r2;
    *(float4*)(ob + 768)     = r3;
}

// ---------------- Kernel C: gather + mean; batch pinned to XCD via blockIdx&7 ----------------
__global__ __launch_bounds__(256) void gather_mean_kernel(const float* __restrict__ f3,
        const int* __restrict__ knn, float* __restrict__ out) {
    int wave = threadIdx.x >> 6, lane = threadIdx.x & 63;
    int b  = blockIdx.x & 7;
    int qg = blockIdx.x >> 3;          // 0..511
    int q  = b * NPTS + qg * 4 + wave;
    const int* kq = knn + (size_t)q * KNN_K;
    const float4* fb = (const float4*)(f3 + (size_t)b * NPTS * 256);
    float4 acc = make_float4(0.f, 0.f, 0.f, 0.f);
#pragma unroll
    for (int k = 0; k < KNN_K; ++k) {
        int j = kq[k];
        float4 v2 = fb[(size_t)j * 64 + lane];
        acc.x += v2.x; acc.y += v2.y; acc.z += v2.z; acc.w += v2.w;
    }
    f32x4 r;
    r.x = acc.x * 0.03125f; r.y = acc.y * 0.03125f;
    r.z = acc.z * 0.03125f; r.w = acc.w * 0.03125f;
    __builtin_nontemporal_store(r, (f32x4*)(out + (size_t)q * 256 + lane * 4));
}

extern "C" void kernel_launch(void* const* d_in, const int* in_sizes, int n_in,
                              void* d_out, int out_size, void* d_ws, size_t ws_size,
                              hipStream_t stream) {
    const float* pts = (const float*)d_in[0];
    const float* W1  = (const float*)d_in[1];
    const float* b1  = (const float*)d_in[2];
    const float* W2  = (const float*)d_in[3];
    const float* b2  = (const float*)d_in[4];
    const float* W3  = (const float*)d_in[5];
    const float* b3  = (const float*)d_in[6];
    float* out = (float*)d_out;
    char* ws = (char*)d_ws;
    int*   knn = (int*)ws;                               // 2 MB
    float* f3  = (float*)(ws + ((size_t)2 << 20));       // 16.8 MB

    hipLaunchKernelGGL(knn_kernel,         dim3(4096), dim3(256), 0, stream, pts, knn);
    hipLaunchKernelGGL(mlp123_kernel,      dim3(1024), dim3(256), 0, stream,
                       pts, W1, b1, W2, b2, W3, b3, f3);
    hipLaunchKernelGGL(gather_mean_kernel, dim3(4096), dim3(256), 0, stream, f3, knn, out);
}